// Round 3
// baseline (10689.966 us; speedup 1.0000x reference)
//
#include <hip/hip_runtime.h>
#include <math.h>

// Problem constants
#define BB 64
#define DD 512
#define VV 10000
#define TT 151
#define NN (BB * TT)          // 9664  — flat (b,t) GEMM N-axis
#define VT (VV * TT)          // 1,510,000
#define RES_ELEMS (BB * VT)   // 96,640,000

// Workspace layout (float units). Total 8,355,840 floats = 33.4 MB.
//  hd0    double[512][64]      @ 0        (65536 f)
//  hd1    double[512][64]      @ 65536    (65536 f)
//  Wihd   double[1536][512]    @ 131072   (1572864 f)
//  Whhd   double[1536][512]    @ 1703936  (1572864 f)
//  SX     float [512][9664]    @ 3276800  (4947968 f)   seq record -> in-place -> X
//  imgT   float [512][64]      @ 8224768  (32768 f)
//  pmax   float [64][4][192]   @ 8257536  (49152 f)
//  pidx   int   [64][4][192]   @ 8306688  (49152 f)

// ---------------- convert GRU weights to double (once per launch) ----------------
__global__ __launch_bounds__(256) void k_cvtw(const float* __restrict__ wih,
                                              const float* __restrict__ whh,
                                              double* __restrict__ wihd,
                                              double* __restrict__ whhd) {
    int i = blockIdx.x * 256 + threadIdx.x;      // grid 3072 -> 786432 exact
    wihd[i] = (double)wih[i];
    whhd[i] = (double)whh[i];
}

// ---------------- transpose img_feat [B][D] -> imgT [D][B] ----------------
__global__ __launch_bounds__(256) void k_tr_img(const float* __restrict__ img,
                                                float* __restrict__ imgT) {
    __shared__ float t[64][65];
    const int d0 = blockIdx.x * 64;
    const int c  = threadIdx.x & 63;
    const int rq = threadIdx.x >> 6;
    for (int r = rq * 16; r < rq * 16 + 16; ++r) t[c][r] = img[r * DD + d0 + c];
    __syncthreads();
    for (int r = rq * 16; r < rq * 16 + 16; ++r) imgT[(d0 + r) * BB + c] = t[r][c];
}

// ---------------- h0 (double) = img @ W_feat.T + b_feat ; SX[:,t=0,:] = embed[0] ----------------
__global__ __launch_bounds__(256) void k_h0(const float* __restrict__ imgT,
                                            const float* __restrict__ W_feat,
                                            const float* __restrict__ b_feat,
                                            const float* __restrict__ embed,
                                            double* __restrict__ h0d,
                                            float* __restrict__ SX) {
    const int tid = threadIdx.x;
    const int b = tid & 63;
    const int w = tid >> 6;
    const int d = blockIdx.x * 4 + w;            // grid 128 -> d 0..511
    const float* __restrict__ wrow = W_feat + d * DD;
    double acc = 0.0;
#pragma unroll 4
    for (int k = 0; k < DD; k += 2) {
        double x0 = (double)imgT[(k + 0) * BB + b];
        double x1 = (double)imgT[(k + 1) * BB + b];
        float2 w2 = *(const float2*)(wrow + k);
        acc = fma(x0, (double)w2.x, acc);
        acc = fma(x1, (double)w2.y, acc);
    }
    h0d[d * BB + b] = acc + (double)b_feat[d];
    SX[(size_t)d * NN + b] = embed[d];           // t = 0 record: embed row 0 broadcast
}

// ---------------- one GRU step, full fp64 (PyTorch gate order r,z,n) ----------------
// MODE 0: x = embed[0] (broadcast), h = hIn.  MODE 1: x == h == hIn.
template <int MODE>
__global__ __launch_bounds__(512) void k_gru(const double* __restrict__ hIn,
                                             double* __restrict__ hOut,
                                             float* __restrict__ SX, int t,
                                             const double* __restrict__ Wihd,
                                             const double* __restrict__ Whhd,
                                             const float* __restrict__ b_ih,
                                             const float* __restrict__ b_hh,
                                             const float* __restrict__ embed) {
    const int tid = threadIdx.x;
    const int b  = tid & 63;
    const int w  = tid >> 6;        // 0..7
    const int jj = w & 1;
    const int dh = w >> 1;          // 0..3
    const int j  = (blockIdx.x << 1) + jj;   // grid 256 -> j 0..511
    const int d0 = dh << 7;

    const double* __restrict__ wir = Wihd + (size_t)j * DD;
    const double* __restrict__ wiz = Wihd + (size_t)(j + DD) * DD;
    const double* __restrict__ win = Wihd + (size_t)(j + 2 * DD) * DD;
    const double* __restrict__ whr = Whhd + (size_t)j * DD;
    const double* __restrict__ whz = Whhd + (size_t)(j + DD) * DD;
    const double* __restrict__ whn = Whhd + (size_t)(j + 2 * DD) * DD;

    double air = 0, aiz = 0, ain = 0, ahr = 0, ahz = 0, ahn = 0;

#pragma unroll 4
    for (int d = d0; d < d0 + 128; d += 2) {
        double h0v = hIn[(d + 0) * BB + b];
        double h1v = hIn[(d + 1) * BB + b];
        double x0, x1;
        if (MODE == 0) { x0 = (double)embed[d]; x1 = (double)embed[d + 1]; }
        else           { x0 = h0v; x1 = h1v; }
        double2 wr = *(const double2*)(wir + d);
        double2 wz = *(const double2*)(wiz + d);
        double2 wn = *(const double2*)(win + d);
        air = fma(x0, wr.x, air); air = fma(x1, wr.y, air);
        aiz = fma(x0, wz.x, aiz); aiz = fma(x1, wz.y, aiz);
        ain = fma(x0, wn.x, ain); ain = fma(x1, wn.y, ain);
        double2 vr = *(const double2*)(whr + d);
        double2 vz = *(const double2*)(whz + d);
        double2 vn = *(const double2*)(whn + d);
        ahr = fma(h0v, vr.x, ahr); ahr = fma(h1v, vr.y, ahr);
        ahz = fma(h0v, vz.x, ahz); ahz = fma(h1v, vz.y, ahz);
        ahn = fma(h0v, vn.x, ahn); ahn = fma(h1v, vn.y, ahn);
    }

    __shared__ double red[6][8][64];
    red[0][w][b] = air; red[1][w][b] = aiz; red[2][w][b] = ain;
    red[3][w][b] = ahr; red[4][w][b] = ahz; red[5][w][b] = ahn;
    __syncthreads();
    if (dh == 0) {   // waves 0,1 finalize the 128 (b,j) pairs
        air += red[0][w + 2][b] + red[0][w + 4][b] + red[0][w + 6][b];
        aiz += red[1][w + 2][b] + red[1][w + 4][b] + red[1][w + 6][b];
        ain += red[2][w + 2][b] + red[2][w + 4][b] + red[2][w + 6][b];
        ahr += red[3][w + 2][b] + red[3][w + 4][b] + red[3][w + 6][b];
        ahz += red[4][w + 2][b] + red[4][w + 4][b] + red[4][w + 6][b];
        ahn += red[5][w + 2][b] + red[5][w + 4][b] + red[5][w + 6][b];
        double rg = air + ahr + (double)b_ih[j] + (double)b_hh[j];
        double zg = aiz + ahz + (double)b_ih[j + DD] + (double)b_hh[j + DD];
        double r = 1.0 / (1.0 + exp(-rg));
        double z = 1.0 / (1.0 + exp(-zg));
        double n = tanh((ain + (double)b_ih[j + 2 * DD]) + r * (ahn + (double)b_hh[j + 2 * DD]));
        double hold = hIn[j * BB + b];
        double hn = (1.0 - z) * n + z * hold;
        hOut[j * BB + b] = hn;
        SX[(size_t)j * NN + t * BB + b] = (float)hn;
    }
}

// ---------------- in-place per-row transpose: SX[d][t*64+b] -> X[d][b*151+t] ----------------
__global__ __launch_bounds__(256) void k_trx(float* __restrict__ SX) {
    __shared__ float l[TT * 65];                 // 39.3 KB
    float* row = SX + (size_t)blockIdx.x * NN;   // grid 512
    for (int i = threadIdx.x; i < NN; i += 256) {
        int t = i >> 6, bc = i & 63;
        l[t * 65 + bc] = row[i];                 // coalesced read; LDS banks ok
    }
    __syncthreads();
    for (int i = threadIdx.x; i < NN; i += 256) {
        int bc = i / TT;
        int t  = i - bc * TT;
        row[i] = l[t * 65 + bc];                 // stride-65 -> conflict-free; coalesced write
    }
}

// ---------------- projection: 10000 x 9664 x 512 GEMM, fp32 FMA + per-32k fp64 combine ----------------
__global__ __launch_bounds__(256) void k_proj(const float* __restrict__ X,
                                              const float* __restrict__ Wp,
                                              const float* __restrict__ bp,
                                              float* __restrict__ res) {
    __shared__ alignas(16) float al[32][64];     // X-tile [k][n]
    __shared__ alignas(16) float bl[32][132];    // W-tile [k][v], pad
    const int tid = threadIdx.x;
    const int n0 = blockIdx.x * 64;              // 151 n-tiles, exact
    const int v0 = blockIdx.y * 128;             // 79 v-tiles
    const int tn = tid & 15, tv = tid >> 4;
    double accD[8][4] = {};

    for (int k0 = 0; k0 < DD; k0 += 32) {
        __syncthreads();
#pragma unroll
        for (int i = 0; i < 8; ++i) {            // stage A: lanes along n -> coalesced
            int idx = tid + i * 256;
            int kr = idx >> 6, nc = idx & 63;
            al[kr][nc] = X[(size_t)(k0 + kr) * NN + n0 + nc];
        }
#pragma unroll
        for (int i = 0; i < 16; ++i) {           // stage B transposed
            int idx = tid + i * 256;
            int vr = idx >> 5, kc = idx & 31;
            int vg = v0 + vr;
            bl[kc][vr] = (vg < VV) ? Wp[(size_t)vg * DD + k0 + kc] : 0.f;
        }
        __syncthreads();
        float acc[8][4] = {};
#pragma unroll 4
        for (int k = 0; k < 32; ++k) {
            float4 a4 = *(const float4*)&al[k][tn * 4];
            float4 b0 = *(const float4*)&bl[k][tv * 4];
            float4 b1 = *(const float4*)&bl[k][64 + tv * 4];
            float av[4] = {a4.x, a4.y, a4.z, a4.w};
            float bv[8] = {b0.x, b0.y, b0.z, b0.w, b1.x, b1.y, b1.z, b1.w};
#pragma unroll
            for (int iv = 0; iv < 8; ++iv)
#pragma unroll
                for (int in = 0; in < 4; ++in)
                    acc[iv][in] += bv[iv] * av[in];
        }
#pragma unroll
        for (int iv = 0; iv < 8; ++iv)
#pragma unroll
            for (int in = 0; in < 4; ++in)
                accD[iv][in] += (double)acc[iv][in];    // chunk-tree: fp64 across 32k chunks
    }

#pragma unroll
    for (int iv = 0; iv < 8; ++iv) {
        int v = v0 + ((iv & 4) << 4) + tv * 4 + (iv & 3);
        if (v >= VV) continue;
        double bias = (double)bp[v];
#pragma unroll
        for (int in = 0; in < 4; ++in) {
            int n = n0 + tn * 4 + in;
            int b = n / TT, t = n - b * TT;
            res[(size_t)b * VT + (size_t)v * TT + t] = (float)(accD[iv][in] + bias);
        }
    }
}

// ---------------- argmax over vocab (softmax monotonic -> skipped) ----------------
__global__ __launch_bounds__(192) void k_amax_p(const float* __restrict__ res,
                                                float* __restrict__ pmax,
                                                int* __restrict__ pidx) {
    const int t = threadIdx.x;
    const int c = blockIdx.x;
    const int b = blockIdx.y;
    if (t >= TT) return;
    const float* base = res + (size_t)b * VT + t;
    float mx = -INFINITY; int mi = 0;
    const int vbeg = c * 2500, vend = vbeg + 2500;
    for (int v = vbeg; v < vend; ++v) {
        float val = base[(size_t)v * TT];
        if (val > mx) { mx = val; mi = v; }      // strict > == first-index tie rule
    }
    pmax[(b * 4 + c) * 192 + t] = mx;
    pidx[(b * 4 + c) * 192 + t] = mi;
}

__global__ __launch_bounds__(192) void k_amax_f(const float* __restrict__ pmax,
                                                const int* __restrict__ pidx,
                                                float* __restrict__ tok) {
    const int t = threadIdx.x;
    const int b = blockIdx.x;
    if (t >= TT) return;
    float mx = pmax[(b * 4 + 0) * 192 + t];
    int   mi = pidx[(b * 4 + 0) * 192 + t];
    for (int c = 1; c < 4; ++c) {
        float m2 = pmax[(b * 4 + c) * 192 + t];
        if (m2 > mx) { mx = m2; mi = pidx[(b * 4 + c) * 192 + t]; }
    }
    tok[b * TT + t] = (float)mi;
}

extern "C" void kernel_launch(void* const* d_in, const int* in_sizes, int n_in,
                              void* d_out, int out_size, void* d_ws, size_t ws_size,
                              hipStream_t stream) {
    const float* img    = (const float*)d_in[0];
    const float* W_feat = (const float*)d_in[1];
    const float* b_feat = (const float*)d_in[2];
    const float* embed  = (const float*)d_in[3];
    const float* W_ih   = (const float*)d_in[4];
    const float* W_hh   = (const float*)d_in[5];
    const float* b_ih   = (const float*)d_in[6];
    const float* b_hh   = (const float*)d_in[7];
    const float* W_proj = (const float*)d_in[8];
    const float* b_proj = (const float*)d_in[9];

    float* res = (float*)d_out;
    float* tok = res + RES_ELEMS;

    float* ws = (float*)d_ws;
    double* hd0  = (double*)(ws);
    double* hd1  = (double*)(ws + 65536);
    double* Wihd = (double*)(ws + 131072);
    double* Whhd = (double*)(ws + 1703936);
    float*  SX   = ws + 3276800;
    float*  imgT = ws + 8224768;
    float*  pmax = ws + 8257536;
    int*    pidx = (int*)(ws + 8306688);

    k_cvtw<<<3072, 256, 0, stream>>>(W_ih, W_hh, Wihd, Whhd);
    k_tr_img<<<8, 256, 0, stream>>>(img, imgT);
    k_h0<<<128, 256, 0, stream>>>(imgT, W_feat, b_feat, embed, hd0, SX);

    // step 1: x = embed[0], h = hd0 -> hd1
    k_gru<0><<<256, 512, 0, stream>>>(hd0, hd1, SX, 1, Wihd, Whhd, b_ih, b_hh, embed);
    // steps 2..150: x == h, ping-pong
    for (int t = 2; t < TT; ++t) {
        const double* hin = (t & 1) ? hd0 : hd1;
        double*       hout = (t & 1) ? hd1 : hd0;
        k_gru<1><<<256, 512, 0, stream>>>(hin, hout, SX, t, Wihd, Whhd, b_ih, b_hh, embed);
    }

    k_trx<<<512, 256, 0, stream>>>(SX);                       // SX -> X in place
    k_proj<<<dim3(151, 79), 256, 0, stream>>>(SX, W_proj, b_proj, res);
    k_amax_p<<<dim3(4, 64), 192, 0, stream>>>(res, pmax, pidx);
    k_amax_f<<<64, 192, 0, stream>>>(pmax, pidx, tok);
}

// Round 5
// 5214.650 us; speedup vs baseline: 2.0500x; 2.0500x over previous
//
#include <hip/hip_runtime.h>
#include <math.h>

// Problem constants
#define BB 64
#define DD 512
#define VV 10000
#define TT 151
#define NN (BB * TT)          // 9664
#define VT (VV * TT)
#define RES_ELEMS (BB * VT)

typedef float f32x4 __attribute__((ext_vector_type(4)));
typedef short bf16x8 __attribute__((ext_vector_type(8)));   // 8 bf16 in 4 VGPRs

// ws layout (float units), total 10,223,104 f = 40.9 MB
//  SX    f32   [512][9664]   @ 0          (trajectory record, [d][t*64+b]; fp32; kept for recheck)
//  Wc    f64   [1024][512]   @ 4947968    (combined r,z weights; DEAD after GRU)
//  Xbf   u16   [9664][512]   @ 4947968    (OVERLAPS Wc; written by k_pack after GRU)
//  Wbf   u16   [10000][512]  @ 7421952
//  cidx  u16   [64][151][16] @ 9981952
//  hd0   f64   [512][64]     @ 10059264
//  hd1   f64   [512][64]     @ 10124800
//  imgT  f32   [512][64]     @ 10190336

__device__ __forceinline__ unsigned short f2bf(float f) {   // RNE fp32->bf16
    unsigned int u = __float_as_uint(f);
    return (unsigned short)((u + 0x7FFFu + ((u >> 16) & 1u)) >> 16);
}

// ---------------- combined r,z weights in fp64 (exact: fp32+fp32 in fp64) ----------------
__global__ __launch_bounds__(256) void k_cvtc(const float* __restrict__ wih,
                                              const float* __restrict__ whh,
                                              double* __restrict__ wc) {
    int i = blockIdx.x * 256 + threadIdx.x;   // grid 2048 -> 524288 exact
    wc[i] = (double)wih[i] + (double)whh[i];
}

// ---------------- W_proj fp32 -> bf16 ----------------
__global__ __launch_bounds__(256) void k_wcvt(const float* __restrict__ wp,
                                              unsigned short* __restrict__ wbf) {
    int i = blockIdx.x * 256 + threadIdx.x;   // grid 20000 -> 5,120,000 exact
    wbf[i] = f2bf(wp[i]);
}

// ---------------- transpose img_feat [B][D] -> imgT [D][B] ----------------
__global__ __launch_bounds__(256) void k_tr_img(const float* __restrict__ img,
                                                float* __restrict__ imgT) {
    __shared__ float t[64][65];
    const int d0 = blockIdx.x * 64;
    const int c  = threadIdx.x & 63;
    const int rq = threadIdx.x >> 6;
    for (int r = rq * 16; r < rq * 16 + 16; ++r) t[c][r] = img[r * DD + d0 + c];
    __syncthreads();
    for (int r = rq * 16; r < rq * 16 + 16; ++r) imgT[(d0 + r) * BB + c] = t[r][c];
}

// ---------------- h0 (double) = img @ W_feat.T + b_feat ; SX[:,t=0,:] = embed[0] ----------------
__global__ __launch_bounds__(256) void k_h0(const float* __restrict__ imgT,
                                            const float* __restrict__ W_feat,
                                            const float* __restrict__ b_feat,
                                            const float* __restrict__ embed,
                                            double* __restrict__ h0d,
                                            float* __restrict__ SX) {
    const int tid = threadIdx.x;
    const int b = tid & 63;
    const int w = tid >> 6;
    const int d = blockIdx.x * 4 + w;            // grid 128 -> d 0..511
    const float* __restrict__ wrow = W_feat + d * DD;
    double acc = 0.0;
#pragma unroll 4
    for (int k = 0; k < DD; k += 2) {
        double x0 = (double)imgT[(k + 0) * BB + b];
        double x1 = (double)imgT[(k + 1) * BB + b];
        float2 w2 = *(const float2*)(wrow + k);
        acc = fma(x0, (double)w2.x, acc);
        acc = fma(x1, (double)w2.y, acc);
    }
    h0d[d * BB + b] = acc + (double)b_feat[d];
    SX[(size_t)d * NN + b] = embed[d];           // t = 0 record: embed row 0 broadcast
}

// ---------------- GRU step t=1: x = embed[0] != h. 6 separate gate streams, fp32 weights. ----------------
__global__ __launch_bounds__(1024) void k_gru0(const double* __restrict__ hIn,
                                               double* __restrict__ hOut,
                                               float* __restrict__ SX,
                                               const float* __restrict__ W_ih,
                                               const float* __restrict__ W_hh,
                                               const float* __restrict__ b_ih,
                                               const float* __restrict__ b_hh,
                                               const float* __restrict__ embed) {
    const int tid = threadIdx.x;
    const int b = tid & 63;
    const int q = tid >> 6;          // 0..15: jl = q&1, dc = q>>1
    const int jl = q & 1;
    const int dc = q >> 1;
    const int j = blockIdx.x * 2 + jl;   // grid 256
    const int d0 = dc * 64;

    const float* __restrict__ wir = W_ih + (size_t)j * DD + d0;
    const float* __restrict__ wiz = W_ih + (size_t)(DD + j) * DD + d0;
    const float* __restrict__ win = W_ih + (size_t)(2 * DD + j) * DD + d0;
    const float* __restrict__ whr = W_hh + (size_t)j * DD + d0;
    const float* __restrict__ whz = W_hh + (size_t)(DD + j) * DD + d0;
    const float* __restrict__ whn = W_hh + (size_t)(2 * DD + j) * DD + d0;
    const double* __restrict__ hp = hIn + (size_t)d0 * BB + b;
    const float* __restrict__ xp = embed + d0;

    double air = 0, aiz = 0, ain = 0, ahr = 0, ahz = 0, ahn = 0;
#pragma unroll 2
    for (int u = 0; u < 64; u += 4) {
        double h0 = hp[(u + 0) * BB];
        double h1 = hp[(u + 1) * BB];
        double h2 = hp[(u + 2) * BB];
        double h3 = hp[(u + 3) * BB];
        float4 x4 = *(const float4*)(xp + u);
        float4 ir4 = *(const float4*)(wir + u);
        float4 iz4 = *(const float4*)(wiz + u);
        float4 in4 = *(const float4*)(win + u);
        float4 hr4 = *(const float4*)(whr + u);
        float4 hz4 = *(const float4*)(whz + u);
        float4 hn4 = *(const float4*)(whn + u);
        air = fma((double)x4.x, (double)ir4.x, air); air = fma((double)x4.y, (double)ir4.y, air);
        air = fma((double)x4.z, (double)ir4.z, air); air = fma((double)x4.w, (double)ir4.w, air);
        aiz = fma((double)x4.x, (double)iz4.x, aiz); aiz = fma((double)x4.y, (double)iz4.y, aiz);
        aiz = fma((double)x4.z, (double)iz4.z, aiz); aiz = fma((double)x4.w, (double)iz4.w, aiz);
        ain = fma((double)x4.x, (double)in4.x, ain); ain = fma((double)x4.y, (double)in4.y, ain);
        ain = fma((double)x4.z, (double)in4.z, ain); ain = fma((double)x4.w, (double)in4.w, ain);
        ahr = fma(h0, (double)hr4.x, ahr); ahr = fma(h1, (double)hr4.y, ahr);
        ahr = fma(h2, (double)hr4.z, ahr); ahr = fma(h3, (double)hr4.w, ahr);
        ahz = fma(h0, (double)hz4.x, ahz); ahz = fma(h1, (double)hz4.y, ahz);
        ahz = fma(h2, (double)hz4.z, ahz); ahz = fma(h3, (double)hz4.w, ahz);
        ahn = fma(h0, (double)hn4.x, ahn); ahn = fma(h1, (double)hn4.y, ahn);
        ahn = fma(h2, (double)hn4.z, ahn); ahn = fma(h3, (double)hn4.w, ahn);
    }

    __shared__ double red[6][16][64];
    red[0][q][b] = air; red[1][q][b] = aiz; red[2][q][b] = ain;
    red[3][q][b] = ahr; red[4][q][b] = ahz; red[5][q][b] = ahn;
    __syncthreads();
    if (q < 2) {                         // q == jl
        double s0 = 0, s1 = 0, s2 = 0, s3 = 0, s4 = 0, s5 = 0;
#pragma unroll
        for (int c = 0; c < 8; ++c) {
            s0 += red[0][c * 2 + q][b]; s1 += red[1][c * 2 + q][b];
            s2 += red[2][c * 2 + q][b]; s3 += red[3][c * 2 + q][b];
            s4 += red[4][c * 2 + q][b]; s5 += red[5][c * 2 + q][b];
        }
        double rg = s0 + s3 + (double)b_ih[j] + (double)b_hh[j];
        double zg = s1 + s4 + (double)b_ih[DD + j] + (double)b_hh[DD + j];
        double r = 1.0 / (1.0 + exp(-rg));
        double z = 1.0 / (1.0 + exp(-zg));
        double n = tanh((s2 + (double)b_ih[2 * DD + j]) + r * (s5 + (double)b_hh[2 * DD + j]));
        double hold = hIn[(size_t)j * BB + b];
        double hn = (1.0 - z) * n + z * hold;
        hOut[(size_t)j * BB + b] = hn;
        SX[(size_t)j * NN + 1 * BB + b] = (float)hn;
    }
}

// ---------------- GRU step t>=2 (x==h): r,z via combined fp64 Wc; n via fp32 W_ih/W_hh ----------------
__global__ __launch_bounds__(1024) void k_gru1(const double* __restrict__ hIn,
                                               double* __restrict__ hOut,
                                               float* __restrict__ SX, int t,
                                               const double* __restrict__ Wc,
                                               const float* __restrict__ W_ih,
                                               const float* __restrict__ W_hh,
                                               const float* __restrict__ b_ih,
                                               const float* __restrict__ b_hh) {
    const int tid = threadIdx.x;
    const int b = tid & 63;
    const int q = tid >> 6;
    const int jl = q & 1;
    const int dc = q >> 1;
    const int j = blockIdx.x * 2 + jl;
    const int d0 = dc * 64;

    const double* __restrict__ wr = Wc + (size_t)j * DD + d0;
    const double* __restrict__ wz = Wc + (size_t)(DD + j) * DD + d0;
    const float* __restrict__ win = W_ih + (size_t)(2 * DD + j) * DD + d0;
    const float* __restrict__ whn = W_hh + (size_t)(2 * DD + j) * DD + d0;
    const double* __restrict__ hp = hIn + (size_t)d0 * BB + b;

    double ar = 0, az = 0, an = 0, ah = 0;
#pragma unroll 2
    for (int u = 0; u < 64; u += 4) {
        double h0 = hp[(u + 0) * BB];
        double h1 = hp[(u + 1) * BB];
        double h2 = hp[(u + 2) * BB];
        double h3 = hp[(u + 3) * BB];
        double2 r01 = *(const double2*)(wr + u);
        double2 r23 = *(const double2*)(wr + u + 2);
        double2 z01 = *(const double2*)(wz + u);
        double2 z23 = *(const double2*)(wz + u + 2);
        float4 wn4 = *(const float4*)(win + u);
        float4 vn4 = *(const float4*)(whn + u);
        ar = fma(h0, r01.x, ar); ar = fma(h1, r01.y, ar);
        ar = fma(h2, r23.x, ar); ar = fma(h3, r23.y, ar);
        az = fma(h0, z01.x, az); az = fma(h1, z01.y, az);
        az = fma(h2, z23.x, az); az = fma(h3, z23.y, az);
        an = fma(h0, (double)wn4.x, an); an = fma(h1, (double)wn4.y, an);
        an = fma(h2, (double)wn4.z, an); an = fma(h3, (double)wn4.w, an);
        ah = fma(h0, (double)vn4.x, ah); ah = fma(h1, (double)vn4.y, ah);
        ah = fma(h2, (double)vn4.z, ah); ah = fma(h3, (double)vn4.w, ah);
    }

    __shared__ double red[4][16][64];
    red[0][q][b] = ar; red[1][q][b] = az; red[2][q][b] = an; red[3][q][b] = ah;
    __syncthreads();
    if (q < 2) {
        double sr = 0, sz = 0, sn = 0, sh = 0;
#pragma unroll
        for (int c = 0; c < 8; ++c) {
            sr += red[0][c * 2 + q][b]; sz += red[1][c * 2 + q][b];
            sn += red[2][c * 2 + q][b]; sh += red[3][c * 2 + q][b];
        }
        double rg = sr + (double)b_ih[j] + (double)b_hh[j];
        double zg = sz + (double)b_ih[DD + j] + (double)b_hh[DD + j];
        double r = 1.0 / (1.0 + exp(-rg));
        double z = 1.0 / (1.0 + exp(-zg));
        double n = tanh((sn + (double)b_ih[2 * DD + j]) + r * (sh + (double)b_hh[2 * DD + j]));
        double hold = hIn[(size_t)j * BB + b];
        double hn = (1.0 - z) * n + z * hold;
        hOut[(size_t)j * BB + b] = hn;
        SX[(size_t)j * NN + (size_t)t * BB + b] = (float)hn;
    }
}

// ---------------- pack: SX [d][t*64+b] f32 -> Xbf [n=b*151+t][d] bf16 ----------------
__global__ __launch_bounds__(256) void k_pack(const float* __restrict__ SX,
                                              unsigned short* __restrict__ Xbf) {
    __shared__ float lt[64][65];
    const int d0 = blockIdx.x * 64;     // 8 d-tiles
    const int t  = blockIdx.y;          // 151
    const int c  = threadIdx.x & 63;
    const int rq = threadIdx.x >> 6;
    for (int dl = rq * 16; dl < rq * 16 + 16; ++dl)
        lt[dl][c] = SX[(size_t)(d0 + dl) * NN + t * BB + c];     // lanes c = b, coalesced
    __syncthreads();
    for (int bl = rq * 16; bl < rq * 16 + 16; ++bl)
        Xbf[(size_t)(bl * TT + t) * DD + d0 + c] = f2bf(lt[c][bl]);  // lanes c = d, coalesced
}

// ---------------- projection via MFMA: res[v][n] = Wbf[v,:] . Xbf[n,:] ----------------
// 128v x 128n tile, 4 waves (wv = w&1 v-half, wn = w>>1 n-half), 16 k-chunks of 32.
// LDS rows pitch 40 u16 (80 B) for even bank-start spread on ds_read_b128 / writes.
__global__ __launch_bounds__(256) void k_pmm(const unsigned short* __restrict__ Xbf,
                                             const unsigned short* __restrict__ Wbf,
                                             const float* __restrict__ bp,
                                             float* __restrict__ res) {
    __shared__ unsigned short As[128 * 40];     // X-tile [n_local][k], 10 KB
    __shared__ unsigned short Bs[128 * 40];     // W-tile [v_local][k], 10 KB
    const int tid = threadIdx.x;
    const int l = tid & 63;
    const int w = tid >> 6;
    const int wv = w & 1, wn = w >> 1;
    const int n0 = blockIdx.x * 128;            // 76 tiles (pad to 9728)
    const int v0 = blockIdx.y * 128;            // 79 tiles (pad to 10112)

    f32x4 acc[4][4];                            // [gi = v-frag][fi = n-frag]
#pragma unroll
    for (int gi = 0; gi < 4; ++gi)
#pragma unroll
        for (int fi = 0; fi < 4; ++fi) acc[gi][fi] = (f32x4){0.f, 0.f, 0.f, 0.f};

    // per-lane fragment byte offsets (row*80 + kgroup*16), fi/gi add 16*80
    const int a_off = (wn * 64 + (l & 15)) * 80 + (l >> 4) * 16;
    const int b_off = (wv * 64 + (l & 15)) * 80 + (l >> 4) * 16;
    // staging map: s = tid + it*256 -> row r = s>>2, part = s&3 (16B of 8 u16)
    const uint4 z4 = {0u, 0u, 0u, 0u};

    for (int c = 0; c < 16; ++c) {
        const int k0 = c * 32;
        __syncthreads();
#pragma unroll
        for (int it = 0; it < 2; ++it) {
            int s = tid + it * 256;
            int r = s >> 2, part = s & 3;
            int ng = n0 + r;
            uint4 va = (ng < NN) ? *(const uint4*)(Xbf + (size_t)ng * DD + k0 + part * 8) : z4;
            *(uint4*)((char*)As + r * 80 + part * 16) = va;
            int vg = v0 + r;
            uint4 vb = (vg < VV) ? *(const uint4*)(Wbf + (size_t)vg * DD + k0 + part * 8) : z4;
            *(uint4*)((char*)Bs + r * 80 + part * 16) = vb;
        }
        __syncthreads();

        bf16x8 af[4], bf[4];
#pragma unroll
        for (int fi = 0; fi < 4; ++fi)
            af[fi] = *(const bf16x8*)((const char*)As + a_off + fi * 16 * 80);
#pragma unroll
        for (int gi = 0; gi < 4; ++gi)
            bf[gi] = *(const bf16x8*)((const char*)Bs + b_off + gi * 16 * 80);
#pragma unroll
        for (int gi = 0; gi < 4; ++gi)
#pragma unroll
            for (int fi = 0; fi < 4; ++fi)
                acc[gi][fi] = __builtin_amdgcn_mfma_f32_16x16x32_bf16(
                    bf[gi], af[fi], acc[gi][fi], 0, 0, 0);   // A = W rows (v), B = X cols (n)
    }

    // epilogue: D col = lane&15 (n), row = (lane>>4)*4 + reg (v)   [m89-verified]
#pragma unroll
    for (int gi = 0; gi < 4; ++gi) {
#pragma unroll
        for (int j = 0; j < 4; ++j) {
            int v = v0 + wv * 64 + gi * 16 + (l >> 4) * 4 + j;
            if (v >= VV) continue;
            float bias = bp[v];
#pragma unroll
            for (int fi = 0; fi < 4; ++fi) {
                int n = n0 + wn * 64 + fi * 16 + (l & 15);
                if (n >= NN) continue;
                int b = n / TT, t = n - b * TT;
                res[(size_t)b * VT + (size_t)v * TT + t] = acc[gi][fi][j] + bias;
            }
        }
    }
}

// ---------------- candidates: per (b,t,chunk-of-2500) top-4 from approx logits ----------------
__global__ __launch_bounds__(192) void k_cand(const float* __restrict__ res,
                                              unsigned short* __restrict__ cidx) {
    const int t = threadIdx.x;
    const int c = blockIdx.x;   // 4 chunks
    const int b = blockIdx.y;
    if (t >= TT) return;
    const float* base = res + (size_t)b * VT + t;
    float v0 = -INFINITY, v1 = -INFINITY, v2 = -INFINITY, v3 = -INFINITY;
    int i0 = 0, i1 = 0, i2 = 0, i3 = 0;
    const int vbeg = c * 2500, vend = vbeg + 2500;
    for (int v = vbeg; v < vend; ++v) {
        float x = base[(size_t)v * TT];          // lanes = consecutive t, coalesced
        if (x > v3) {
            if (x > v1) {
                if (x > v0) { v3 = v2; i3 = i2; v2 = v1; i2 = i1; v1 = v0; i1 = i0; v0 = x; i0 = v; }
                else        { v3 = v2; i3 = i2; v2 = v1; i2 = i1; v1 = x; i1 = v; }
            } else {
                if (x > v2) { v3 = v2; i3 = i2; v2 = x; i2 = v; }
                else        { v3 = x; i3 = v; }
            }
        }
    }
    unsigned short* o = cidx + ((size_t)(b * TT + t) * 16 + c * 4);
    o[0] = (unsigned short)i0; o[1] = (unsigned short)i1;
    o[2] = (unsigned short)i2; o[3] = (unsigned short)i3;
}

// ---------------- exact fp64 recheck of 16 candidates -> tokens ----------------
__global__ __launch_bounds__(64) void k_rech(const float* __restrict__ SX,
                                             const float* __restrict__ Wp,
                                             const float* __restrict__ bp,
                                             const unsigned short* __restrict__ cidx,
                                             float* __restrict__ tok) {
    const int t = blockIdx.x;    // 151
    const int b = blockIdx.y;    // 64
    const int tid = threadIdx.x;
    __shared__ float xv[512];
    __shared__ double pd[64];
    __shared__ double cval[16];
    __shared__ int cvi[16];
#pragma unroll
    for (int i = 0; i < 8; ++i)
        xv[i * 64 + tid] = SX[(size_t)(i * 64 + tid) * NN + t * BB + b];
    __syncthreads();
    const int ci = tid >> 2, part = tid & 3;
    const int v = (int)cidx[(size_t)(b * TT + t) * 16 + ci];
    const float* wrow = Wp + (size_t)v * DD + part * 128;
    const float* xp = xv + part * 128;
    double s = 0.0;
#pragma unroll 4
    for (int d = 0; d < 128; ++d) s = fma((double)xp[d], (double)wrow[d], s);
    pd[tid] = s;
    __syncthreads();
    if (part == 0) {
        cval[ci] = pd[tid] + pd[tid + 1] + pd[tid + 2] + pd[tid + 3] + (double)bp[v];
        cvi[ci] = v;
    }
    __syncthreads();
    if (tid == 0) {
        double best = -INFINITY; int bi = 1 << 30;
        for (int k = 0; k < 16; ++k) {
            double val = cval[k]; int vv = cvi[k];
            if (val > best || (val == best && vv < bi)) { best = val; bi = vv; }
        }
        tok[b * TT + t] = (float)bi;
    }
}

extern "C" void kernel_launch(void* const* d_in, const int* in_sizes, int n_in,
                              void* d_out, int out_size, void* d_ws, size_t ws_size,
                              hipStream_t stream) {
    const float* img    = (const float*)d_in[0];
    const float* W_feat = (const float*)d_in[1];
    const float* b_feat = (const float*)d_in[2];
    const float* embed  = (const float*)d_in[3];
    const float* W_ih   = (const float*)d_in[4];
    const float* W_hh   = (const float*)d_in[5];
    const float* b_ih   = (const float*)d_in[6];
    const float* b_hh   = (const float*)d_in[7];
    const float* W_proj = (const float*)d_in[8];
    const float* b_proj = (const float*)d_in[9];

    float* res = (float*)d_out;
    float* tok = res + RES_ELEMS;

    float* ws = (float*)d_ws;
    float*          SX   = ws;
    double*         Wc   = (double*)(ws + 4947968);        // dead after GRU
    unsigned short* Xbf  = (unsigned short*)(ws + 4947968);// overlaps Wc, written after GRU
    unsigned short* Wbf  = (unsigned short*)(ws + 7421952);
    unsigned short* cidx = (unsigned short*)(ws + 9981952);
    double*         hd0  = (double*)(ws + 10059264);
    double*         hd1  = (double*)(ws + 10124800);
    float*          imgT = ws + 10190336;

    k_cvtc<<<2048, 256, 0, stream>>>(W_ih, W_hh, Wc);
    k_wcvt<<<20000, 256, 0, stream>>>(W_proj, Wbf);
    k_tr_img<<<8, 256, 0, stream>>>(img, imgT);
    k_h0<<<128, 256, 0, stream>>>(imgT, W_feat, b_feat, embed, hd0, SX);

    // t = 1: x = embed[0], h = hd0 -> hd1
    k_gru0<<<256, 1024, 0, stream>>>(hd0, hd1, SX, W_ih, W_hh, b_ih, b_hh, embed);
    // t = 2..150: x == h, ping-pong
    for (int t = 2; t < TT; ++t) {
        const double* hin  = (t & 1) ? hd0 : hd1;
        double*       hout = (t & 1) ? hd1 : hd0;
        k_gru1<<<256, 1024, 0, stream>>>(hin, hout, SX, t, Wc, W_ih, W_hh, b_ih, b_hh);
    }

    k_pack<<<dim3(8, TT), 256, 0, stream>>>(SX, Xbf);          // Wc dead from here
    k_pmm<<<dim3(76, 79), 256, 0, stream>>>(Xbf, Wbf, b_proj, res);
    k_cand<<<dim3(4, 64), 192, 0, stream>>>(res, cidx);
    k_rech<<<dim3(TT, 64), 64, 0, stream>>>(SX, W_proj, b_proj, cidx, tok);
}